// Round 6
// baseline (145.103 us; speedup 1.0000x reference)
//
#include <hip/hip_runtime.h>
#include <hip/hip_bf16.h>
#include <cstdint>

typedef __attribute__((ext_vector_type(8))) short short8;
typedef __attribute__((ext_vector_type(4))) float f32x4;

#define BDIM 32
#define CDIM 2048
#define NPIX 196    // 14*14
#define HIN 14
#define N2 784      // 28*28
#define W2 28
#define KDIM 113
#define KC 112
#define NCLS 200
#define BN 112      // cols per block; 7*112 = 784 exact
#define NSTEP 64    // 2048/32
#define SMLD 117    // Sm row stride (conflict-free)
#define PSTR 36     // k_xe transposed plane stride

// ---------------- K_prep: concepts -> bf16, PRE-PERMUTED to LDS fragment order, + csq ----------------
__global__ __launch_bounds__(256) void k_prep(const float* __restrict__ concepts,
                                              ushort* __restrict__ cbf,
                                              float* __restrict__ csq) {
  int k = blockIdx.x, t = threadIdx.x;
  const int kt = k >> 4, lr = k & 15;
  float s = 0.f;
  for (int c = t; c < CDIM; c += 256) {
    float v = (k < KDIM) ? concepts[(size_t)k * CDIM + c] : 0.f;
    __hip_bfloat16 h = __float2bfloat16(v);
    int st = c >> 5, gs = (c >> 3) & 3, j = c & 7;
    cbf[((((size_t)st * 8 + kt) * 4 + gs) * 16 + lr) * 8 + j] = __bfloat16_as_ushort(h);
    float vb = __bfloat162float(h);
    s = fmaf(vb, vb, s);
  }
  __shared__ float r[4];
#pragma unroll
  for (int off = 32; off > 0; off >>= 1) s += __shfl_down(s, off, 64);
  if ((t & 63) == 0) r[t >> 6] = s;
  __syncthreads();
  if (t == 0) csq[k] = r[0] + r[1] + r[2] + r[3];
}

// ---------------- K_xe: upsample once -> bf16 xep in exact LDS fragment image ----------------
__global__ __launch_bounds__(512) void k_xe(const float* __restrict__ x,
                                            ushort* __restrict__ xep) {
  __shared__ float P[NPIX][PSTR];  // transposed planes: P[pix][ch]
  const int s = blockIdx.x, b = blockIdx.y;
  const int tid = threadIdx.x;
  const float* src = x + ((size_t)b * CDIM + s * 32) * NPIX;
  {
    const int cl = tid >> 4, p0 = tid & 15;
#pragma unroll
    for (int k = 0; k < 13; ++k) {
      int p = p0 + (k << 4);
      if (p < NPIX) P[p][cl] = src[cl * NPIX + p];
    }
  }
  __syncthreads();
  if (tid >= 448) return;
  const int t = tid >> 6, gs = (tid >> 4) & 3, lr = tid & 15;
  const int nn = t * 16 + lr;
  const int gs8 = gs * 8;
  for (int bx = 0; bx < 7; ++bx) {
    const int n = bx * BN + nn;
    int i2 = n / W2, j2 = n - i2 * W2;
    float si = 0.5f * i2 - 0.25f;
    float sj = 0.5f * j2 - 0.25f;
    float fif = floorf(si), fjf = floorf(sj);
    int ii = (int)fif, jj = (int)fjf;
    float fi = si - fif, fj = sj - fjf;
    int ia = ii < 0 ? 0 : ii;
    int ib = (ii + 1 > 13) ? 13 : (ii + 1);
    int ja = jj < 0 ? 0 : jj;
    int jb = (jj + 1 > 13) ? 13 : (jj + 1);
    const float w00 = (1.f - fi) * (1.f - fj), w01 = (1.f - fi) * fj;
    const float w10 = fi * (1.f - fj),         w11 = fi * fj;
    const int o00 = ia * HIN + ja, o01 = ia * HIN + jb;
    const int o10 = ib * HIN + ja, o11 = ib * HIN + jb;
    float T00[8], T01[8], T10[8], T11[8];
    *(float4*)&T00[0] = *(const float4*)&P[o00][gs8];
    *(float4*)&T00[4] = *(const float4*)&P[o00][gs8 + 4];
    *(float4*)&T01[0] = *(const float4*)&P[o01][gs8];
    *(float4*)&T01[4] = *(const float4*)&P[o01][gs8 + 4];
    *(float4*)&T10[0] = *(const float4*)&P[o10][gs8];
    *(float4*)&T10[4] = *(const float4*)&P[o10][gs8 + 4];
    *(float4*)&T11[0] = *(const float4*)&P[o11][gs8];
    *(float4*)&T11[4] = *(const float4*)&P[o11][gs8 + 4];
    uint us[4];
#pragma unroll
    for (int p = 0; p < 4; ++p) {
      float v0 = w00 * T00[2 * p] + w01 * T01[2 * p] + w10 * T10[2 * p] + w11 * T11[2 * p];
      float v1 = w00 * T00[2 * p + 1] + w01 * T01[2 * p + 1] + w10 * T10[2 * p + 1] + w11 * T11[2 * p + 1];
      us[p] = (uint)__bfloat16_as_ushort(__float2bfloat16(v0)) |
              ((uint)__bfloat16_as_ushort(__float2bfloat16(v1)) << 16);
    }
    uint4 pk; pk.x = us[0]; pk.y = us[1]; pk.z = us[2]; pk.w = us[3];
    *(uint4*)&xep[(((size_t)(b * 7 + bx) * 64 + s) * 3584) + (size_t)tid * 8] = pk;
  }
}

// ---------------- K_gemm: 4-deep reg-ring prefetch MFMA GEMM + parallel softmax epilogue ----------------
__global__ __launch_bounds__(512) void k_gemm(
    const ushort* __restrict__ xep,      // pre-permuted bf16 xe
    const ushort* __restrict__ cbf,      // pre-permuted bf16 concepts
    const float* __restrict__ cfcw,      // [2048]
    const float* __restrict__ csq,       // [128]
    float* __restrict__ attn_out,        // [32][113][784]
    float* __restrict__ part)            // [32][7][112]
{
  union SmemU {
    struct { ushort A[2][4096]; ushort B[2][3584]; } ab;
    float Sm[128][SMLD];
  };
  __shared__ SmemU u;
  __shared__ float cfcw_s[CDIM];
  __shared__ float red[4][BN][2];
  __shared__ float xsq[BN], proj[BN], csq_s[KDIM], rinv_s[BN];

  const int tid = threadIdx.x;
  const int b = blockIdx.y, bx = blockIdx.x;
  const int n0 = bx * BN;
  const int lane = tid & 63, w = tid >> 6;
  const int lr = lane & 15, gs = lane >> 4;
  const bool bact = tid < 448;
  const int g = (tid >> 4) & 3;                    // staged channel group
  const int nn = (tid >> 6) * 16 + (tid & 15);     // staged column

  for (int i = tid; i < CDIM; i += 512) cfcw_s[i] = cfcw[i];
  if (tid < KDIM) csq_s[tid] = csq[tid];
  __syncthreads();   // cfcw_s is read cross-wave in the first stage() below

  const ushort* xb = xep + (size_t)(b * 7 + bx) * 64 * 3584;
  float psq = 0.f, ppj = 0.f;

  f32x4 acc[7];
#pragma unroll
  for (int t = 0; t < 7; ++t) acc[t] = f32x4{0.f, 0.f, 0.f, 0.f};

  // stage slot -> LDS buf + psq/ppj side computation (av/bv passed by value; slot
  // indices are compile-time at every call site after unrolling)
  auto stage = [&](uint4 av, uint4 bv, int bufi, int c0) {
    *(uint4*)&u.ab.A[bufi][tid * 8] = av;
    if (bact) {
      *(uint4*)&u.ab.B[bufi][tid * 8] = bv;
      uint uu[4] = {bv.x, bv.y, bv.z, bv.w};
#pragma unroll
      for (int p = 0; p < 4; ++p) {
        float v0 = __uint_as_float(uu[p] << 16);
        float v1 = __uint_as_float(uu[p] & 0xffff0000u);
        psq = fmaf(v0, v0, psq);
        psq = fmaf(v1, v1, psq);
        ppj = fmaf(v0, cfcw_s[c0 + g * 8 + p * 2], ppj);
        ppj = fmaf(v1, cfcw_s[c0 + g * 8 + p * 2 + 1], ppj);
      }
    }
  };

  // ---- prologue: fill 4-slot register ring with steps 0..3; stage step 0 ----
  uint4 ra[4] = {};
  uint4 rb[4] = {};
#pragma unroll
  for (int j = 0; j < 4; ++j) {
    ra[j] = *(const uint4*)(cbf + (size_t)j * 4096 + tid * 8);
    if (bact) rb[j] = *(const uint4*)(xb + (size_t)j * 3584 + tid * 8);
  }
  stage(ra[0], rb[0], 0, 0);
  __syncthreads();

  // ---- main loop: MFMA(s) | issue load s+4 | stage s+1 | barrier ----
  for (int sb = 0; sb < NSTEP; sb += 4) {
#pragma unroll
    for (int j = 0; j < 4; ++j) {
      const int s = sb + j;
      {
        short8 af = *(const short8*)&u.ab.A[j & 1][w * 512 + lane * 8];
#pragma unroll
        for (int t = 0; t < 7; ++t) {
          short8 bfr = *(const short8*)&u.ab.B[j & 1][t * 512 + lane * 8];
          acc[t] = __builtin_amdgcn_mfma_f32_16x16x32_bf16(af, bfr, acc[t], 0, 0, 0);
        }
      }
      if (s + 4 < NSTEP) {
        ra[j] = *(const uint4*)(cbf + (size_t)(s + 4) * 4096 + tid * 8);
        if (bact) rb[j] = *(const uint4*)(xb + (size_t)(s + 4) * 3584 + tid * 8);
      }
      if (s + 1 < NSTEP) {
        stage(ra[(j + 1) & 3], rb[(j + 1) & 3], (j + 1) & 1, (s + 1) * 32);
        __syncthreads();
      }
    }
  }

  // ---- reduce x_sq / proj across the 4 channel-groups ----
  if (bact) { red[g][nn][0] = psq; red[g][nn][1] = ppj; }
  __syncthreads();
  if (tid < BN) {
    float sq = 0.f, pj = 0.f;
#pragma unroll
    for (int gg = 0; gg < 4; ++gg) { sq += red[gg][tid][0]; pj += red[gg][tid][1]; }
    xsq[tid] = sq; proj[tid] = pj;
  }
  __syncthreads();

  // ---- d2 -> -dist into Sm (C/D layout: col=lane&15, row=(lane>>4)*4+reg) ----
#pragma unroll
  for (int t = 0; t < 7; ++t) {
    int col = t * 16 + lr;
#pragma unroll
    for (int q = 0; q < 4; ++q) {
      int k = w * 16 + gs * 4 + q;
      if (k < KDIM) {
        float d2 = csq_s[k] + xsq[col] - 2.f * acc[t][q];
        u.Sm[k][col] = -sqrtf(fmaxf(d2, 0.f));
      }
    }
  }
  __syncthreads();

  // ---- softmax: 4 lanes per column (quad shfl_xor reductions) ----
  {
    const int col = tid >> 2, sub = tid & 3;
    if (col < BN) {
      float m = -1e30f;
      for (int k = sub; k < KDIM; k += 4) m = fmaxf(m, u.Sm[k][col]);
      m = fmaxf(m, __shfl_xor(m, 1, 64));
      m = fmaxf(m, __shfl_xor(m, 2, 64));
      float ssum = 0.f;
      for (int k = sub; k < KDIM; k += 4) {
        float e = __expf(u.Sm[k][col] - m);
        u.Sm[k][col] = e;
        ssum += e;
      }
      ssum += __shfl_xor(ssum, 1, 64);
      ssum += __shfl_xor(ssum, 2, 64);
      if (sub == 0) rinv_s[col] = 1.f / ssum;
    }
  }
  __syncthreads();

  // ---- normalize + write attn: 8-wave coalesced (lane sweep over columns) ----
  {
    const int col2 = tid & 127, kr = tid >> 7;
    if (col2 < BN) {
      const float rv = rinv_s[col2];
      float* op = attn_out + (size_t)b * KDIM * N2 + n0 + col2;
      for (int k = kr; k < KDIM; k += 4) {
        float a2 = u.Sm[k][col2] * rv;
        u.Sm[k][col2] = a2;
        op[(size_t)k * N2] = a2;
      }
    }
  }
  __syncthreads();

  // ---- logit partials: quad-parallel over columns ----
  if (tid < KC * 4) {
    const int k = tid >> 2, sub = tid & 3;
    float lg = 0.f;
    for (int c2 = sub; c2 < BN; c2 += 4) lg = fmaf(u.Sm[k][c2], proj[c2], lg);
    lg += __shfl_xor(lg, 1, 64);
    lg += __shfl_xor(lg, 2, 64);
    if (sub == 0) part[((size_t)b * 7 + bx) * KC + k] = lg;
  }
}

// ---------------- K_main fallback (used if ws too small) ----------------
__global__ __launch_bounds__(512) void k_main_fb(
    const float* __restrict__ x, const ushort* __restrict__ cbf,
    const float* __restrict__ cfcw, const float* __restrict__ csq,
    float* __restrict__ attn_out, float* __restrict__ part)
{
  union SmemU {
    struct { ushort A[2][4096]; ushort B[2][3584]; } ab;
    float Sm[128][SMLD];
  };
  __shared__ SmemU u;
  __shared__ float cfcw_s[CDIM];
  __shared__ float red[4][BN][2];
  __shared__ float xsq[BN], proj[BN], csq_s[KDIM];

  const int tid = threadIdx.x;
  const int b = blockIdx.y, bx = blockIdx.x;
  const int n0 = bx * BN;
  const int lane = tid & 63, w = tid >> 6;
  const int lr = lane & 15, gs = lane >> 4;
  const bool bact = tid < 448;
  const int g = tid / BN;
  const int nn = tid - g * BN;
  const int boff = (((nn >> 4) * 4 + g) * 16 + (nn & 15)) * 8;

  int n = n0 + nn;
  int i2 = n / W2, j2 = n - i2 * W2;
  float si = 0.5f * i2 - 0.25f;
  float sj = 0.5f * j2 - 0.25f;
  float fif = floorf(si), fjf = floorf(sj);
  int ii = (int)fif, jj = (int)fjf;
  float fi = si - fif, fj = sj - fjf;
  int ia = ii < 0 ? 0 : ii;
  int ib = (ii + 1 > 13) ? 13 : (ii + 1);
  int ja = jj < 0 ? 0 : jj;
  int jb = (jj + 1 > 13) ? 13 : (jj + 1);
  const float w00 = (1.f - fi) * (1.f - fj), w01 = (1.f - fi) * fj;
  const float w10 = fi * (1.f - fj),         w11 = fi * fj;
  const int o00 = ia * HIN + ja, o01 = ia * HIN + jb;
  const int o10 = ib * HIN + ja, o11 = ib * HIN + jb;

  for (int i = tid; i < CDIM; i += 512) cfcw_s[i] = cfcw[i];
  if (tid < KDIM) csq_s[tid] = csq[tid];
  __syncthreads();

  const float* xb = x + (size_t)b * CDIM * NPIX;
  float psq = 0.f, ppj = 0.f;

  f32x4 acc[7];
#pragma unroll
  for (int t = 0; t < 7; ++t) acc[t] = f32x4{0.f, 0.f, 0.f, 0.f};

  for (int s = -1; s < NSTEP; ++s) {
    const bool more = (s + 1) < NSTEP;
    uint4 a_st;
    float bv[8];
    if (more) {
      const int c0n = (s + 1) * 32;
      a_st = *(const uint4*)(cbf + (size_t)(s + 1) * 4096 + tid * 8);
      if (bact) {
#pragma unroll
        for (int j = 0; j < 8; ++j) {
          const float* xr = xb + (size_t)(c0n + g * 8 + j) * NPIX;
          bv[j] = w00 * xr[o00] + w01 * xr[o01] + w10 * xr[o10] + w11 * xr[o11];
        }
      }
    }
    if (s >= 0) {
      const int cb = s & 1;
      short8 af = *(const short8*)&u.ab.A[cb][w * 512 + lane * 8];
#pragma unroll
      for (int t = 0; t < 7; ++t) {
        short8 bfr = *(const short8*)&u.ab.B[cb][t * 512 + lane * 8];
        acc[t] = __builtin_amdgcn_mfma_f32_16x16x32_bf16(af, bfr, acc[t], 0, 0, 0);
      }
    }
    if (more) {
      const int nb = (s + 1) & 1;
      const int c0n = (s + 1) * 32;
      *(uint4*)&u.ab.A[nb][tid * 8] = a_st;
      if (bact) {
        uint us[4];
#pragma unroll
        for (int p = 0; p < 4; ++p) {
          __hip_bfloat16 h0 = __float2bfloat16(bv[p * 2]);
          __hip_bfloat16 h1 = __float2bfloat16(bv[p * 2 + 1]);
          float v0 = __bfloat162float(h0), v1 = __bfloat162float(h1);
          psq = fmaf(v0, v0, psq);
          psq = fmaf(v1, v1, psq);
          ppj = fmaf(v0, cfcw_s[c0n + g * 8 + p * 2], ppj);
          ppj = fmaf(v1, cfcw_s[c0n + g * 8 + p * 2 + 1], ppj);
          us[p] = (uint)__bfloat16_as_ushort(h0) | ((uint)__bfloat16_as_ushort(h1) << 16);
        }
        uint4 pk; pk.x = us[0]; pk.y = us[1]; pk.z = us[2]; pk.w = us[3];
        *(uint4*)&u.ab.B[nb][boff] = pk;
      }
    }
    __syncthreads();
  }

  if (bact) { red[g][nn][0] = psq; red[g][nn][1] = ppj; }
  __syncthreads();
  if (tid < BN) {
    float sq = 0.f, pj = 0.f;
#pragma unroll
    for (int gg = 0; gg < 4; ++gg) { sq += red[gg][tid][0]; pj += red[gg][tid][1]; }
    xsq[tid] = sq; proj[tid] = pj;
  }
  __syncthreads();

#pragma unroll
  for (int t = 0; t < 7; ++t) {
    int col = t * 16 + lr;
#pragma unroll
    for (int q = 0; q < 4; ++q) {
      int k = w * 16 + gs * 4 + q;
      if (k < KDIM) {
        float d2 = csq_s[k] + xsq[col] - 2.f * acc[t][q];
        u.Sm[k][col] = -sqrtf(fmaxf(d2, 0.f));
      }
    }
  }
  __syncthreads();

  if (tid < BN) {
    const int col = tid;
    float m = -1e30f;
    for (int k = 0; k < KDIM; ++k) m = fmaxf(m, u.Sm[k][col]);
    float sum = 0.f;
    for (int k = 0; k < KDIM; ++k) {
      float e = __expf(u.Sm[k][col] - m);
      u.Sm[k][col] = e;
      sum += e;
    }
    float rinv = 1.f / sum;
    float* op = attn_out + (size_t)b * KDIM * N2 + n0 + col;
    for (int k = 0; k < KDIM; ++k) {
      float a2 = u.Sm[k][col] * rinv;
      u.Sm[k][col] = a2;
      op[(size_t)k * N2] = a2;
    }
  }
  __syncthreads();

  if (tid < KC) {
    float lg = 0.f;
    for (int c2 = 0; c2 < BN; ++c2) lg = fmaf(u.Sm[tid][c2], proj[c2], lg);
    part[((size_t)b * 7 + bx) * KC + tid] = lg;
  }
}

// ---------------- K4: reduce partials -> sigmoid -> concept_scores ----------------
__global__ void k_sig(const float* __restrict__ part, const float* __restrict__ cfcb,
                      float* __restrict__ cs_out) {
  int i = blockIdx.x * blockDim.x + threadIdx.x;
  if (i >= BDIM * KC) return;
  int b = i / KC, k = i % KC;
  float l = cfcb[0];
#pragma unroll
  for (int t = 0; t < 7; ++t) l += part[((size_t)b * 7 + t) * KC + k];
  cs_out[i] = 1.f / (1.f + __expf(-l));
}

// ---------------- K5a: tmp[b,c] = sum_k cs[b,k] * concepts[k,c] ----------------
__global__ __launch_bounds__(256) void k_tmp(
    const float* __restrict__ concepts, const float* __restrict__ cs,
    float* __restrict__ tmp) {
  __shared__ float cs_s[KC];
  const int b = blockIdx.y;
  const int c = blockIdx.x * 256 + threadIdx.x;
  if (threadIdx.x < KC) cs_s[threadIdx.x] = cs[b * KC + threadIdx.x];
  __syncthreads();
  float a = 0.f;
#pragma unroll 8
  for (int k = 0; k < KC; ++k) a = fmaf(cs_s[k], concepts[(size_t)k * CDIM + c], a);
  tmp[(size_t)b * CDIM + c] = a;
}

// ---------------- K5b: preds[b,cls] = tmp[b,:].labw[cls,:] + labb ----------------
__global__ __launch_bounds__(256) void k_pred2(
    const float* __restrict__ labw, const float* __restrict__ labb,
    const float* __restrict__ tmp, float* __restrict__ preds) {
  const int w = blockIdx.x * 4 + (threadIdx.x >> 6);
  const int lane = threadIdx.x & 63;
  const int b = w / NCLS, cls = w % NCLS;
  if (b >= BDIM) return;
  const float* tr = tmp + (size_t)b * CDIM;
  const float* wr = labw + (size_t)cls * CDIM;
  float a = 0.f;
#pragma unroll
  for (int c0 = 0; c0 < CDIM; c0 += 256) {
    float4 t = *(const float4*)&tr[c0 + lane * 4];
    float4 v = *(const float4*)&wr[c0 + lane * 4];
    a += t.x * v.x + t.y * v.y + t.z * v.z + t.w * v.w;
  }
#pragma unroll
  for (int off = 32; off > 0; off >>= 1) a += __shfl_down(a, off, 64);
  if (lane == 0) preds[b * NCLS + cls] = a + labb[cls];
}

extern "C" void kernel_launch(void* const* d_in, const int* in_sizes, int n_in,
                              void* d_out, int out_size, void* d_ws, size_t ws_size,
                              hipStream_t stream) {
  const float* x        = (const float*)d_in[0];
  const float* concepts = (const float*)d_in[1];
  const float* cfcw     = (const float*)d_in[2];
  const float* cfcb     = (const float*)d_in[3];
  const float* labw     = (const float*)d_in[4];
  const float* labb     = (const float*)d_in[5];

  float* out    = (float*)d_out;
  float* sm_out = out;                                  // [32][113][784]
  float* cs_out = out + (size_t)BDIM * KDIM * N2;       // [32][112]
  float* pr_out = cs_out + (size_t)BDIM * KC;           // [32][200]

  char* ws = (char*)d_ws;
  float*  csq  = (float*)(ws + 0);         // 128 f32          -> 512 B
  float*  part = (float*)(ws + 512);       // 32*7*112 f32     -> 100,352 B
  float*  tmp  = (float*)(ws + 100864);    // 32*2048 f32      -> 262,144 B
  ushort* cbf  = (ushort*)(ws + 363008);   // 128*2048 bf16    -> 524,288 B
  ushort* xep  = (ushort*)(ws + 887296);   // 32*7*64*3584 bf16 -> 102,760,448 B
  const size_t need_fast = 887296 + (size_t)BDIM * 7 * 64 * 3584 * 2;

  k_prep<<<dim3(128), dim3(256), 0, stream>>>(concepts, cbf, csq);
  if (ws_size >= need_fast) {
    k_xe  <<<dim3(64, BDIM), dim3(512), 0, stream>>>(x, xep);
    k_gemm<<<dim3(7, BDIM), dim3(512), 0, stream>>>(xep, cbf, cfcw, csq, sm_out, part);
  } else {
    k_main_fb<<<dim3(7, BDIM), dim3(512), 0, stream>>>(x, cbf, cfcw, csq, sm_out, part);
  }
  k_sig <<<dim3((BDIM * KC + 255) / 256), dim3(256), 0, stream>>>(part, cfcb, cs_out);
  k_tmp <<<dim3(CDIM / 256, BDIM), dim3(256), 0, stream>>>(concepts, cs_out, tmp);
  k_pred2<<<dim3((BDIM * NCLS + 3) / 4), dim3(256), 0, stream>>>(labw, labb, tmp, pr_out);
}

// Round 7
// 107.177 us; speedup vs baseline: 1.3539x; 1.3539x over previous
//
#include <hip/hip_runtime.h>
#include <hip/hip_bf16.h>
#include <cstdint>

typedef __attribute__((ext_vector_type(8))) short short8;
typedef __attribute__((ext_vector_type(4))) float f32x4;

#define BDIM 32
#define CDIM 2048
#define NPIX 196    // 14*14
#define HIN 14
#define N2 784      // 28*28
#define W2 28
#define KDIM 113
#define KC 112
#define NCLS 200
#define BN 112      // cols per block; 7*112 = 784 exact
#define NSTEP 64    // 2048/32
#define SMLD 117    // Sm row stride (conflict-free)
#define PSTR 36     // k_xe transposed plane stride

// ---------------- K_prep: concepts -> bf16, PRE-PERMUTED to per-wave fragment order, + csq ----------------
__global__ __launch_bounds__(256) void k_prep(const float* __restrict__ concepts,
                                              ushort* __restrict__ cbf,
                                              float* __restrict__ csq) {
  int k = blockIdx.x, t = threadIdx.x;
  const int kt = k >> 4, lr = k & 15;
  float s = 0.f;
  for (int c = t; c < CDIM; c += 256) {
    float v = (k < KDIM) ? concepts[(size_t)k * CDIM + c] : 0.f;
    __hip_bfloat16 h = __float2bfloat16(v);
    int st = c >> 5, gs = (c >> 3) & 3, j = c & 7;
    cbf[((((size_t)st * 8 + kt) * 4 + gs) * 16 + lr) * 8 + j] = __bfloat16_as_ushort(h);
    float vb = __bfloat162float(h);
    s = fmaf(vb, vb, s);
  }
  __shared__ float r[4];
#pragma unroll
  for (int off = 32; off > 0; off >>= 1) s += __shfl_down(s, off, 64);
  if ((t & 63) == 0) r[t >> 6] = s;
  __syncthreads();
  if (t == 0) csq[k] = r[0] + r[1] + r[2] + r[3];
}

// ---------------- K_xe: upsample once -> bf16 xep in exact fragment image ----------------
__global__ __launch_bounds__(512) void k_xe(const float* __restrict__ x,
                                            ushort* __restrict__ xep) {
  __shared__ float P[NPIX][PSTR];  // transposed planes: P[pix][ch]
  const int s = blockIdx.x, b = blockIdx.y;
  const int tid = threadIdx.x;
  const float* src = x + ((size_t)b * CDIM + s * 32) * NPIX;
  {
    const int cl = tid >> 4, p0 = tid & 15;
#pragma unroll
    for (int k = 0; k < 13; ++k) {
      int p = p0 + (k << 4);
      if (p < NPIX) P[p][cl] = src[cl * NPIX + p];
    }
  }
  __syncthreads();
  if (tid >= 448) return;
  const int t = tid >> 6, gs = (tid >> 4) & 3, lr = tid & 15;
  const int nn = t * 16 + lr;
  const int gs8 = gs * 8;
  for (int bx = 0; bx < 7; ++bx) {
    const int n = bx * BN + nn;
    int i2 = n / W2, j2 = n - i2 * W2;
    float si = 0.5f * i2 - 0.25f;
    float sj = 0.5f * j2 - 0.25f;
    float fif = floorf(si), fjf = floorf(sj);
    int ii = (int)fif, jj = (int)fjf;
    float fi = si - fif, fj = sj - fjf;
    int ia = ii < 0 ? 0 : ii;
    int ib = (ii + 1 > 13) ? 13 : (ii + 1);
    int ja = jj < 0 ? 0 : jj;
    int jb = (jj + 1 > 13) ? 13 : (jj + 1);
    const float w00 = (1.f - fi) * (1.f - fj), w01 = (1.f - fi) * fj;
    const float w10 = fi * (1.f - fj),         w11 = fi * fj;
    const int o00 = ia * HIN + ja, o01 = ia * HIN + jb;
    const int o10 = ib * HIN + ja, o11 = ib * HIN + jb;
    float T00[8], T01[8], T10[8], T11[8];
    *(float4*)&T00[0] = *(const float4*)&P[o00][gs8];
    *(float4*)&T00[4] = *(const float4*)&P[o00][gs8 + 4];
    *(float4*)&T01[0] = *(const float4*)&P[o01][gs8];
    *(float4*)&T01[4] = *(const float4*)&P[o01][gs8 + 4];
    *(float4*)&T10[0] = *(const float4*)&P[o10][gs8];
    *(float4*)&T10[4] = *(const float4*)&P[o10][gs8 + 4];
    *(float4*)&T11[0] = *(const float4*)&P[o11][gs8];
    *(float4*)&T11[4] = *(const float4*)&P[o11][gs8 + 4];
    uint us[4];
#pragma unroll
    for (int p = 0; p < 4; ++p) {
      float v0 = w00 * T00[2 * p] + w01 * T01[2 * p] + w10 * T10[2 * p] + w11 * T11[2 * p];
      float v1 = w00 * T00[2 * p + 1] + w01 * T01[2 * p + 1] + w10 * T10[2 * p + 1] + w11 * T11[2 * p + 1];
      us[p] = (uint)__bfloat16_as_ushort(__float2bfloat16(v0)) |
              ((uint)__bfloat16_as_ushort(__float2bfloat16(v1)) << 16);
    }
    uint4 pk; pk.x = us[0]; pk.y = us[1]; pk.z = us[2]; pk.w = us[3];
    *(uint4*)&xep[(((size_t)(b * 7 + bx) * 64 + s) * 3584) + (size_t)tid * 8] = pk;
  }
}

// ---------------- K_gemm: barrier-free all-register MFMA GEMM + parallel epilogue ----------------
__global__ __launch_bounds__(512) void k_gemm(
    const ushort* __restrict__ xep,      // pre-permuted bf16 xe
    const ushort* __restrict__ cbf,      // pre-permuted bf16 concepts
    const float* __restrict__ cfcw,      // [2048]
    const float* __restrict__ csq,       // [128]
    float* __restrict__ attn_out,        // [32][113][784]
    float* __restrict__ part)            // [32][7][112]
{
  __shared__ float Sm[128][SMLD];        // 59.9 KB
  __shared__ float xsq[BN], proj[BN], csq_s[KDIM], rinv_s[BN];

  const int tid = threadIdx.x;
  const int b = blockIdx.y, bx = blockIdx.x;
  const int n0 = bx * BN;
  const int lane = tid & 63, w = tid >> 6;     // wave w owns k-rows w*16..w*16+15
  const int lr = lane & 15, gs = lane >> 4;
  const bool pact = (w < 7);                   // waves 0..6 accumulate psq/ppj (tile w)

  if (tid < KDIM) csq_s[tid] = csq[tid];

  const ushort* xb = xep + (size_t)(b * 7 + bx) * 64 * 3584;
  const ushort* abp = cbf + w * 512 + lane * 8;    // + s*4096 per step

  // rotated tile offsets: b?[j] holds tile (w+j)%7 -> psq tile is always b?[0]
  int tof[7];
#pragma unroll
  for (int j = 0; j < 7; ++j) {
    int tile = w + j; if (tile >= 7) tile -= 7; if (tile >= 7) tile -= 7;
    tof[j] = tile * 512 + lane * 8;
  }

  f32x4 acc[7];
#pragma unroll
  for (int j = 0; j < 7; ++j) acc[j] = f32x4{0.f, 0.f, 0.f, 0.f};
  float psq = 0.f, ppj = 0.f;

#define LOADSET(A_, B_, S_)                                              \
  do {                                                                   \
    const int s_ = (S_);                                                 \
    A_ = *(const uint4*)(abp + (size_t)s_ * 4096);                       \
    const ushort* xbs_ = xb + (size_t)s_ * 3584;                         \
    _Pragma("unroll")                                                    \
    for (int j_ = 0; j_ < 7; ++j_) B_[j_] = *(const uint4*)(xbs_ + tof[j_]); \
  } while (0)

#define COMPUTE(A_, B_, S_)                                              \
  do {                                                                   \
    const int s_ = (S_);                                                 \
    short8 af_ = *(const short8*)&A_;                                    \
    _Pragma("unroll")                                                    \
    for (int j_ = 0; j_ < 7; ++j_) {                                     \
      short8 bf_ = *(const short8*)&B_[j_];                              \
      acc[j_] = __builtin_amdgcn_mfma_f32_16x16x32_bf16(af_, bf_, acc[j_], 0, 0, 0); \
    }                                                                    \
    if (pact) {                                                          \
      float cw_[8];                                                      \
      *(float4*)&cw_[0] = *(const float4*)(cfcw + s_ * 32 + gs * 8);     \
      *(float4*)&cw_[4] = *(const float4*)(cfcw + s_ * 32 + gs * 8 + 4); \
      uint uu_[4] = {B_[0].x, B_[0].y, B_[0].z, B_[0].w};                \
      _Pragma("unroll")                                                  \
      for (int p_ = 0; p_ < 4; ++p_) {                                   \
        float v0_ = __uint_as_float(uu_[p_] << 16);                      \
        float v1_ = __uint_as_float(uu_[p_] & 0xffff0000u);              \
        psq = fmaf(v0_, v0_, psq);                                       \
        psq = fmaf(v1_, v1_, psq);                                       \
        ppj = fmaf(v0_, cw_[2 * p_], ppj);                               \
        ppj = fmaf(v1_, cw_[2 * p_ + 1], ppj);                           \
      }                                                                  \
    }                                                                    \
  } while (0)

  uint4 a0, a1, b0[7], b1[7];
  LOADSET(a0, b0, 0);
  for (int s = 0; s < NSTEP; s += 2) {
    if (s + 1 < NSTEP) LOADSET(a1, b1, s + 1);
    COMPUTE(a0, b0, s);
    if (s + 2 < NSTEP) LOADSET(a0, b0, s + 2);
    COMPUTE(a1, b1, s + 1);
  }
#undef LOADSET
#undef COMPUTE

  // ---- xsq/proj: reduce over gs groups via shfl, lanes 0..15 publish ----
  if (pact) {
    psq += __shfl_xor(psq, 16, 64);
    psq += __shfl_xor(psq, 32, 64);
    ppj += __shfl_xor(ppj, 16, 64);
    ppj += __shfl_xor(ppj, 32, 64);
    if (lane < 16) { xsq[w * 16 + lane] = psq; proj[w * 16 + lane] = ppj; }
  }
  __syncthreads();

  // ---- d2 -> -dist into Sm (C/D: col=lane&15, row=(lane>>4)*4+reg; tile=(w+j)%7) ----
#pragma unroll
  for (int j = 0; j < 7; ++j) {
    int tile = w + j; if (tile >= 7) tile -= 7; if (tile >= 7) tile -= 7;
    int col = tile * 16 + lr;
#pragma unroll
    for (int q = 0; q < 4; ++q) {
      int k = w * 16 + gs * 4 + q;
      if (k < KDIM) {
        float d2 = csq_s[k] + xsq[col] - 2.f * acc[j][q];
        Sm[k][col] = -sqrtf(fmaxf(d2, 0.f));
      }
    }
  }
  __syncthreads();

  // ---- softmax: 4 lanes per column ----
  {
    const int col = tid >> 2, sub = tid & 3;
    if (col < BN) {
      float m = -1e30f;
      for (int k = sub; k < KDIM; k += 4) m = fmaxf(m, Sm[k][col]);
      m = fmaxf(m, __shfl_xor(m, 1, 64));
      m = fmaxf(m, __shfl_xor(m, 2, 64));
      float ssum = 0.f;
      for (int k = sub; k < KDIM; k += 4) {
        float e = __expf(Sm[k][col] - m);
        Sm[k][col] = e;
        ssum += e;
      }
      ssum += __shfl_xor(ssum, 1, 64);
      ssum += __shfl_xor(ssum, 2, 64);
      if (sub == 0) rinv_s[col] = 1.f / ssum;
    }
  }
  __syncthreads();

  // ---- normalize + write attn: coalesced lane sweep over columns ----
  {
    const int col2 = tid & 127, kr = tid >> 7;
    if (col2 < BN) {
      const float rv = rinv_s[col2];
      float* op = attn_out + (size_t)b * KDIM * N2 + n0 + col2;
      for (int k = kr; k < KDIM; k += 4) {
        float a2 = Sm[k][col2] * rv;
        Sm[k][col2] = a2;
        op[(size_t)k * N2] = a2;
      }
    }
  }
  __syncthreads();

  // ---- logit partials: quad-parallel over columns ----
  if (tid < KC * 4) {
    const int k = tid >> 2, sub = tid & 3;
    float lg = 0.f;
    for (int c2 = sub; c2 < BN; c2 += 4) lg = fmaf(Sm[k][c2], proj[c2], lg);
    lg += __shfl_xor(lg, 1, 64);
    lg += __shfl_xor(lg, 2, 64);
    if (sub == 0) part[((size_t)b * 7 + bx) * KC + k] = lg;
  }
}

// ---------------- K_main fallback (used if ws too small) ----------------
__global__ __launch_bounds__(512) void k_main_fb(
    const float* __restrict__ x, const ushort* __restrict__ cbf,
    const float* __restrict__ cfcw, const float* __restrict__ csq,
    float* __restrict__ attn_out, float* __restrict__ part)
{
  union SmemU {
    struct { ushort A[2][4096]; ushort B[2][3584]; } ab;
    float Sm[128][SMLD];
  };
  __shared__ SmemU u;
  __shared__ float cfcw_s[CDIM];
  __shared__ float red[4][BN][2];
  __shared__ float xsq[BN], proj[BN], csq_s[KDIM];

  const int tid = threadIdx.x;
  const int b = blockIdx.y, bx = blockIdx.x;
  const int n0 = bx * BN;
  const int lane = tid & 63, w = tid >> 6;
  const int lr = lane & 15, gs = lane >> 4;
  const bool bact = tid < 448;
  const int g = tid / BN;
  const int nn = tid - g * BN;
  const int boff = (((nn >> 4) * 4 + g) * 16 + (nn & 15)) * 8;

  int n = n0 + nn;
  int i2 = n / W2, j2 = n - i2 * W2;
  float si = 0.5f * i2 - 0.25f;
  float sj = 0.5f * j2 - 0.25f;
  float fif = floorf(si), fjf = floorf(sj);
  int ii = (int)fif, jj = (int)fjf;
  float fi = si - fif, fj = sj - fjf;
  int ia = ii < 0 ? 0 : ii;
  int ib = (ii + 1 > 13) ? 13 : (ii + 1);
  int ja = jj < 0 ? 0 : jj;
  int jb = (jj + 1 > 13) ? 13 : (jj + 1);
  const float w00 = (1.f - fi) * (1.f - fj), w01 = (1.f - fi) * fj;
  const float w10 = fi * (1.f - fj),         w11 = fi * fj;
  const int o00 = ia * HIN + ja, o01 = ia * HIN + jb;
  const int o10 = ib * HIN + ja, o11 = ib * HIN + jb;

  for (int i = tid; i < CDIM; i += 512) cfcw_s[i] = cfcw[i];
  if (tid < KDIM) csq_s[tid] = csq[tid];
  __syncthreads();

  const float* xb = x + (size_t)b * CDIM * NPIX;
  float psq = 0.f, ppj = 0.f;

  f32x4 acc[7];
#pragma unroll
  for (int t = 0; t < 7; ++t) acc[t] = f32x4{0.f, 0.f, 0.f, 0.f};

  for (int s = -1; s < NSTEP; ++s) {
    const bool more = (s + 1) < NSTEP;
    uint4 a_st;
    float bv[8];
    if (more) {
      const int c0n = (s + 1) * 32;
      a_st = *(const uint4*)(cbf + (size_t)(s + 1) * 4096 + tid * 8);
      if (bact) {
#pragma unroll
        for (int j = 0; j < 8; ++j) {
          const float* xr = xb + (size_t)(c0n + g * 8 + j) * NPIX;
          bv[j] = w00 * xr[o00] + w01 * xr[o01] + w10 * xr[o10] + w11 * xr[o11];
        }
      }
    }
    if (s >= 0) {
      const int cb = s & 1;
      short8 af = *(const short8*)&u.ab.A[cb][w * 512 + lane * 8];
#pragma unroll
      for (int t = 0; t < 7; ++t) {
        short8 bfr = *(const short8*)&u.ab.B[cb][t * 512 + lane * 8];
        acc[t] = __builtin_amdgcn_mfma_f32_16x16x32_bf16(af, bfr, acc[t], 0, 0, 0);
      }
    }
    if (more) {
      const int nb = (s + 1) & 1;
      const int c0n = (s + 1) * 32;
      *(uint4*)&u.ab.A[nb][tid * 8] = a_st;
      if (bact) {
        uint us[4];
#pragma unroll
        for (int p = 0; p < 4; ++p) {
          __hip_bfloat16 h0 = __float2bfloat16(bv[p * 2]);
          __hip_bfloat16 h1 = __float2bfloat16(bv[p * 2 + 1]);
          float v0 = __bfloat162float(h0), v1 = __bfloat162float(h1);
          psq = fmaf(v0, v0, psq);
          psq = fmaf(v1, v1, psq);
          ppj = fmaf(v0, cfcw_s[c0n + g * 8 + p * 2], ppj);
          ppj = fmaf(v1, cfcw_s[c0n + g * 8 + p * 2 + 1], ppj);
          us[p] = (uint)__bfloat16_as_ushort(h0) | ((uint)__bfloat16_as_ushort(h1) << 16);
        }
        uint4 pk; pk.x = us[0]; pk.y = us[1]; pk.z = us[2]; pk.w = us[3];
        *(uint4*)&u.ab.B[nb][boff] = pk;
      }
    }
    __syncthreads();
  }

  if (bact) { red[g][nn][0] = psq; red[g][nn][1] = ppj; }
  __syncthreads();
  if (tid < BN) {
    float sq = 0.f, pj = 0.f;
#pragma unroll
    for (int gg = 0; gg < 4; ++gg) { sq += red[gg][tid][0]; pj += red[gg][tid][1]; }
    xsq[tid] = sq; proj[tid] = pj;
  }
  __syncthreads();

#pragma unroll
  for (int t = 0; t < 7; ++t) {
    int col = t * 16 + lr;
#pragma unroll
    for (int q = 0; q < 4; ++q) {
      int k = w * 16 + gs * 4 + q;
      if (k < KDIM) {
        float d2 = csq_s[k] + xsq[col] - 2.f * acc[t][q];
        u.Sm[k][col] = -sqrtf(fmaxf(d2, 0.f));
      }
    }
  }
  __syncthreads();

  if (tid < BN) {
    const int col = tid;
    float m = -1e30f;
    for (int k = 0; k < KDIM; ++k) m = fmaxf(m, u.Sm[k][col]);
    float sum = 0.f;
    for (int k = 0; k < KDIM; ++k) {
      float e = __expf(u.Sm[k][col] - m);
      u.Sm[k][col] = e;
      sum += e;
    }
    float rinv = 1.f / sum;
    float* op = attn_out + (size_t)b * KDIM * N2 + n0 + col;
    for (int k = 0; k < KDIM; ++k) {
      float a2 = u.Sm[k][col] * rinv;
      u.Sm[k][col] = a2;
      op[(size_t)k * N2] = a2;
    }
  }
  __syncthreads();

  if (tid < KC) {
    float lg = 0.f;
    for (int c2 = 0; c2 < BN; ++c2) lg = fmaf(u.Sm[tid][c2], proj[c2], lg);
    part[((size_t)b * 7 + bx) * KC + tid] = lg;
  }
}

// ---------------- K4: reduce partials -> sigmoid -> concept_scores ----------------
__global__ void k_sig(const float* __restrict__ part, const float* __restrict__ cfcb,
                      float* __restrict__ cs_out) {
  int i = blockIdx.x * blockDim.x + threadIdx.x;
  if (i >= BDIM * KC) return;
  int b = i / KC, k = i % KC;
  float l = cfcb[0];
#pragma unroll
  for (int t = 0; t < 7; ++t) l += part[((size_t)b * 7 + t) * KC + k];
  cs_out[i] = 1.f / (1.f + __expf(-l));
}

// ---------------- K5a: tmp[b,c] = sum_k cs[b,k] * concepts[k,c] ----------------
__global__ __launch_bounds__(256) void k_tmp(
    const float* __restrict__ concepts, const float* __restrict__ cs,
    float* __restrict__ tmp) {
  __shared__ float cs_s[KC];
  const int b = blockIdx.y;
  const int c = blockIdx.x * 256 + threadIdx.x;
  if (threadIdx.x < KC) cs_s[threadIdx.x] = cs[b * KC + threadIdx.x];
  __syncthreads();
  float a = 0.f;
#pragma unroll 8
  for (int k = 0; k < KC; ++k) a = fmaf(cs_s[k], concepts[(size_t)k * CDIM + c], a);
  tmp[(size_t)b * CDIM + c] = a;
}

// ---------------- K5b: preds[b,cls] = tmp[b,:].labw[cls,:] + labb ----------------
__global__ __launch_bounds__(256) void k_pred2(
    const float* __restrict__ labw, const float* __restrict__ labb,
    const float* __restrict__ tmp, float* __restrict__ preds) {
  const int w = blockIdx.x * 4 + (threadIdx.x >> 6);
  const int lane = threadIdx.x & 63;
  const int b = w / NCLS, cls = w % NCLS;
  if (b >= BDIM) return;
  const float* tr = tmp + (size_t)b * CDIM;
  const float* wr = labw + (size_t)cls * CDIM;
  float a = 0.f;
#pragma unroll
  for (int c0 = 0; c0 < CDIM; c0 += 256) {
    float4 t = *(const float4*)&tr[c0 + lane * 4];
    float4 v = *(const float4*)&wr[c0 + lane * 4];
    a += t.x * v.x + t.y * v.y + t.z * v.z + t.w * v.w;
  }
#pragma unroll
  for (int off = 32; off > 0; off >>= 1) a += __shfl_down(a, off, 64);
  if (lane == 0) preds[b * NCLS + cls] = a + labb[cls];
}

extern "C" void kernel_launch(void* const* d_in, const int* in_sizes, int n_in,
                              void* d_out, int out_size, void* d_ws, size_t ws_size,
                              hipStream_t stream) {
  const float* x        = (const float*)d_in[0];
  const float* concepts = (const float*)d_in[1];
  const float* cfcw     = (const float*)d_in[2];
  const float* cfcb     = (const float*)d_in[3];
  const float* labw     = (const float*)d_in[4];
  const float* labb     = (const float*)d_in[5];

  float* out    = (float*)d_out;
  float* sm_out = out;                                  // [32][113][784]
  float* cs_out = out + (size_t)BDIM * KDIM * N2;       // [32][112]
  float* pr_out = cs_out + (size_t)BDIM * KC;           // [32][200]

  char* ws = (char*)d_ws;
  float*  csq  = (float*)(ws + 0);         // 128 f32          -> 512 B
  float*  part = (float*)(ws + 512);       // 32*7*112 f32     -> 100,352 B
  float*  tmp  = (float*)(ws + 100864);    // 32*2048 f32      -> 262,144 B
  ushort* cbf  = (ushort*)(ws + 363008);   // 128*2048 bf16    -> 524,288 B
  ushort* xep  = (ushort*)(ws + 887296);   // 32*7*64*3584 bf16 -> 102,760,448 B
  const size_t need_fast = 887296 + (size_t)BDIM * 7 * 64 * 3584 * 2;

  k_prep<<<dim3(128), dim3(256), 0, stream>>>(concepts, cbf, csq);
  if (ws_size >= need_fast) {
    k_xe  <<<dim3(64, BDIM), dim3(512), 0, stream>>>(x, xep);
    k_gemm<<<dim3(7, BDIM), dim3(512), 0, stream>>>(xep, cbf, cfcw, csq, sm_out, part);
  } else {
    k_main_fb<<<dim3(7, BDIM), dim3(512), 0, stream>>>(x, cbf, cfcw, csq, sm_out, part);
  }
  k_sig <<<dim3((BDIM * KC + 255) / 256), dim3(256), 0, stream>>>(part, cfcb, cs_out);
  k_tmp <<<dim3(CDIM / 256, BDIM), dim3(256), 0, stream>>>(concepts, cs_out, tmp);
  k_pred2<<<dim3((BDIM * NCLS + 3) / 4), dim3(256), 0, stream>>>(labw, labb, tmp, pr_out);
}

// Round 8
// 103.497 us; speedup vs baseline: 1.4020x; 1.0356x over previous
//
#include <hip/hip_runtime.h>
#include <hip/hip_bf16.h>
#include <cstdint>

typedef __attribute__((ext_vector_type(8))) short short8;
typedef __attribute__((ext_vector_type(4))) float f32x4;

#define BDIM 32
#define CDIM 2048
#define NPIX 196    // 14*14
#define HIN 14
#define N2 784      // 28*28
#define W2 28
#define KDIM 113
#define KC 112
#define NCLS 200
#define BN 112      // cols per block; 7*112 = 784 exact
#define NSTEP 64    // 2048/32
#define SMLD 117    // Sm row stride (conflict-free)
#define PPAD 6276   // 32*196 + 4 pad (safe for the weight-0 pair over-read)

// ---------------- K_prep: concepts -> bf16, PRE-PERMUTED to LDS fragment order, + csq ----------------
__global__ __launch_bounds__(256) void k_prep(const float* __restrict__ concepts,
                                              ushort* __restrict__ cbf,
                                              float* __restrict__ csq) {
  int k = blockIdx.x, t = threadIdx.x;
  const int kt = k >> 4, lr = k & 15;
  float s = 0.f;
  for (int c = t; c < CDIM; c += 256) {
    float v = (k < KDIM) ? concepts[(size_t)k * CDIM + c] : 0.f;
    __hip_bfloat16 h = __float2bfloat16(v);
    int st = c >> 5, gs = (c >> 3) & 3, j = c & 7;
    cbf[((((size_t)st * 8 + kt) * 4 + gs) * 16 + lr) * 8 + j] = __bfloat16_as_ushort(h);
    float vb = __bfloat162float(h);
    s = fmaf(vb, vb, s);
  }
  __shared__ float r[4];
#pragma unroll
  for (int off = 32; off > 0; off >>= 1) s += __shfl_down(s, off, 64);
  if ((t & 63) == 0) r[t >> 6] = s;
  __syncthreads();
  if (t == 0) csq[k] = r[0] + r[1] + r[2] + r[3];
}

// ---------------- K_fused: LDS-staged upsample + bf16 MFMA dist GEMM + softmax + logit partials ----------------
__global__ __launch_bounds__(512) void k_fused(
    const float* __restrict__ x,         // [32][2048][14][14]
    const ushort* __restrict__ cbf,      // pre-permuted bf16 concepts
    const float* __restrict__ cfcw,      // [2048]
    const float* __restrict__ csq,       // [128]
    float* __restrict__ attn_out,        // [32][113][784]
    float* __restrict__ part)            // [32][7][112]
{
  union alignas(16) SmemU {
    struct { float P[2][PPAD]; ushort A[2][4096]; ushort Bf[2][3584]; } s;  // 80.9 KB
    float Sm[128][SMLD];                                                    // 59.9 KB
  };
  __shared__ SmemU u;
  __shared__ float cfcw_s[CDIM];
  __shared__ float red[4][BN][2];
  __shared__ float xsq[BN], proj[BN], csq_s[KDIM], rinv_s[BN];

  const int tid = threadIdx.x;
  const int b = blockIdx.y, bx = blockIdx.x;
  const int n0 = bx * BN;
  const int lane = tid & 63, w = tid >> 6;   // wave w owns k-rows w*16..w*16+15
  const int lr = lane & 15, gs = lane >> 4;
  const bool bact = tid < 448;
  const int g = tid / BN;                    // channel group 0..3 (bact)
  const int nn = tid - g * BN;               // column 0..111
  const int boff = (((nn >> 4) * 4 + g) * 16 + (nn & 15)) * 8;

  // bilinear params for col n0+nn (src = 0.5*o - 0.25, edge-clamped), pair-read form:
  // read [o00,o00+1] and [o10,o10+1]; when jb==ja fold the j-weights (second tap weight 0)
  int n = n0 + (bact ? nn : 0);
  int i2 = n / W2, j2 = n - i2 * W2;
  float si = 0.5f * i2 - 0.25f;
  float sj = 0.5f * j2 - 0.25f;
  float fif = floorf(si), fjf = floorf(sj);
  int ii = (int)fif, jj = (int)fjf;
  float fi = si - fif, fj = sj - fjf;
  int ia = ii < 0 ? 0 : ii;
  int ib = (ii + 1 > 13) ? 13 : (ii + 1);
  int ja = jj < 0 ? 0 : jj;
  int jb = (jj + 1 > 13) ? 13 : (jj + 1);
  float w00 = (1.f - fi) * (1.f - fj), w01 = (1.f - fi) * fj;
  float w10 = fi * (1.f - fj),         w11 = fi * fj;
  if (jb == ja) { w00 += w01; w01 = 0.f; w10 += w11; w11 = 0.f; }
  const int o00 = ia * HIN + ja;
  const int o10 = ib * HIN + ja;

  for (int i = tid; i < CDIM; i += 512) cfcw_s[i] = cfcw[i];
  if (tid < KDIM) csq_s[tid] = csq[tid];

  const float* xb = x + (size_t)b * CDIM * NPIX;
  float psq = 0.f, ppj = 0.f;

  f32x4 acc[7];
#pragma unroll
  for (int t = 0; t < 7; ++t) acc[t] = f32x4{0.f, 0.f, 0.f, 0.f};

  float4 q0, q1, q2, q3 = {0.f, 0.f, 0.f, 0.f};
  uint4 av;

  // ---- prologue: stage step 0 (x slice is 32*196 contiguous floats = 1568 float4) ----
  {
    const float4* ps = (const float4*)xb;
    q0 = ps[tid]; q1 = ps[tid + 512]; q2 = ps[tid + 1024];
    if (tid < 32) q3 = ps[tid + 1536];
    av = *(const uint4*)(cbf + (size_t)tid * 8);
    *(float4*)&u.s.P[0][tid * 4] = q0;
    *(float4*)&u.s.P[0][(tid + 512) * 4] = q1;
    *(float4*)&u.s.P[0][(tid + 1024) * 4] = q2;
    if (tid < 32) *(float4*)&u.s.P[0][(tid + 1536) * 4] = q3;
    *(uint4*)&u.s.A[0][tid * 8] = av;
  }
  __syncthreads();

  // ---- main loop: issue s+1 | blend s | write s+1 | barrier | MFMA s | barrier ----
  for (int s = 0; s < NSTEP; ++s) {
    const int cur = s & 1, nxt = cur ^ 1;
    const bool more = (s + 1) < NSTEP;
    if (more) {
      const float4* ps = (const float4*)(xb + (size_t)(s + 1) * 32 * NPIX);
      q0 = ps[tid]; q1 = ps[tid + 512]; q2 = ps[tid + 1024];
      if (tid < 32) q3 = ps[tid + 1536];
      av = *(const uint4*)(cbf + (size_t)(s + 1) * 4096 + tid * 8);
    }
    if (bact) {
      const float* Pc = u.s.P[cur];
      const int cb0 = s * 32 + g * 8;
      uint us_[4];
#pragma unroll
      for (int p = 0; p < 4; ++p) {
        float vv[2];
#pragma unroll
        for (int h = 0; h < 2; ++h) {
          const int j = p * 2 + h;
          const float* pr = Pc + (g * 8 + j) * NPIX;
          float a0 = pr[o00], a1 = pr[o00 + 1];   // ds_read2_b32 pair
          float b0 = pr[o10], b1 = pr[o10 + 1];
          vv[h] = w00 * a0 + w01 * a1 + w10 * b0 + w11 * b1;
        }
        __hip_bfloat16 h0 = __float2bfloat16(vv[0]);
        __hip_bfloat16 h1 = __float2bfloat16(vv[1]);
        float v0 = __bfloat162float(h0), v1 = __bfloat162float(h1);
        psq = fmaf(v0, v0, psq);
        psq = fmaf(v1, v1, psq);
        ppj = fmaf(v0, cfcw_s[cb0 + p * 2], ppj);
        ppj = fmaf(v1, cfcw_s[cb0 + p * 2 + 1], ppj);
        us_[p] = (uint)__bfloat16_as_ushort(h0) | ((uint)__bfloat16_as_ushort(h1) << 16);
      }
      uint4 pk; pk.x = us_[0]; pk.y = us_[1]; pk.z = us_[2]; pk.w = us_[3];
      *(uint4*)&u.s.Bf[cur][boff] = pk;
    }
    if (more) {
      *(float4*)&u.s.P[nxt][tid * 4] = q0;
      *(float4*)&u.s.P[nxt][(tid + 512) * 4] = q1;
      *(float4*)&u.s.P[nxt][(tid + 1024) * 4] = q2;
      if (tid < 32) *(float4*)&u.s.P[nxt][(tid + 1536) * 4] = q3;
      *(uint4*)&u.s.A[nxt][tid * 8] = av;
    }
    __syncthreads();
    {
      short8 af = *(const short8*)&u.s.A[cur][w * 512 + lane * 8];
#pragma unroll
      for (int t = 0; t < 7; ++t) {
        short8 bfr = *(const short8*)&u.s.Bf[cur][t * 512 + lane * 8];
        acc[t] = __builtin_amdgcn_mfma_f32_16x16x32_bf16(af, bfr, acc[t], 0, 0, 0);
      }
    }
    __syncthreads();
  }

  // ---- reduce x_sq / proj across the 4 channel-groups ----
  if (bact) { red[g][nn][0] = psq; red[g][nn][1] = ppj; }
  __syncthreads();
  if (tid < BN) {
    float sq = 0.f, pj = 0.f;
#pragma unroll
    for (int gg = 0; gg < 4; ++gg) { sq += red[gg][tid][0]; pj += red[gg][tid][1]; }
    xsq[tid] = sq; proj[tid] = pj;
  }
  __syncthreads();

  // ---- d2 -> -dist into Sm (C/D layout: col=lane&15, row=(lane>>4)*4+reg) ----
#pragma unroll
  for (int t = 0; t < 7; ++t) {
    int col = t * 16 + lr;
#pragma unroll
    for (int q = 0; q < 4; ++q) {
      int k = w * 16 + gs * 4 + q;
      if (k < KDIM) {
        float d2 = csq_s[k] + xsq[col] - 2.f * acc[t][q];
        u.Sm[k][col] = -sqrtf(fmaxf(d2, 0.f));
      }
    }
  }
  __syncthreads();

  // ---- softmax: 4 lanes per column (quad shfl_xor reductions) ----
  {
    const int col = tid >> 2, sub = tid & 3;
    if (col < BN) {
      float m = -1e30f;
      for (int k = sub; k < KDIM; k += 4) m = fmaxf(m, u.Sm[k][col]);
      m = fmaxf(m, __shfl_xor(m, 1, 64));
      m = fmaxf(m, __shfl_xor(m, 2, 64));
      float ssum = 0.f;
      for (int k = sub; k < KDIM; k += 4) {
        float e = __expf(u.Sm[k][col] - m);
        u.Sm[k][col] = e;
        ssum += e;
      }
      ssum += __shfl_xor(ssum, 1, 64);
      ssum += __shfl_xor(ssum, 2, 64);
      if (sub == 0) rinv_s[col] = 1.f / ssum;
    }
  }
  __syncthreads();

  // ---- normalize + write attn: coalesced lane sweep over columns ----
  {
    const int col2 = tid & 127, kr = tid >> 7;
    if (col2 < BN) {
      const float rv = rinv_s[col2];
      float* op = attn_out + (size_t)b * KDIM * N2 + n0 + col2;
      for (int k = kr; k < KDIM; k += 4) {
        float a2 = u.Sm[k][col2] * rv;
        u.Sm[k][col2] = a2;
        op[(size_t)k * N2] = a2;
      }
    }
  }
  __syncthreads();

  // ---- logit partials: quad-parallel over columns ----
  if (tid < KC * 4) {
    const int k = tid >> 2, sub = tid & 3;
    float lg = 0.f;
    for (int c2 = sub; c2 < BN; c2 += 4) lg = fmaf(u.Sm[k][c2], proj[c2], lg);
    lg += __shfl_xor(lg, 1, 64);
    lg += __shfl_xor(lg, 2, 64);
    if (sub == 0) part[((size_t)b * 7 + bx) * KC + k] = lg;
  }
}

// ---------------- K4: reduce partials -> sigmoid -> concept_scores ----------------
__global__ void k_sig(const float* __restrict__ part, const float* __restrict__ cfcb,
                      float* __restrict__ cs_out) {
  int i = blockIdx.x * blockDim.x + threadIdx.x;
  if (i >= BDIM * KC) return;
  int b = i / KC, k = i % KC;
  float l = cfcb[0];
#pragma unroll
  for (int t = 0; t < 7; ++t) l += part[((size_t)b * 7 + t) * KC + k];
  cs_out[i] = 1.f / (1.f + __expf(-l));
}

// ---------------- K5a: tmp[b,c] = sum_k cs[b,k] * concepts[k,c] ----------------
__global__ __launch_bounds__(256) void k_tmp(
    const float* __restrict__ concepts, const float* __restrict__ cs,
    float* __restrict__ tmp) {
  __shared__ float cs_s[KC];
  const int b = blockIdx.y;
  const int c = blockIdx.x * 256 + threadIdx.x;
  if (threadIdx.x < KC) cs_s[threadIdx.x] = cs[b * KC + threadIdx.x];
  __syncthreads();
  float a = 0.f;
#pragma unroll 8
  for (int k = 0; k < KC; ++k) a = fmaf(cs_s[k], concepts[(size_t)k * CDIM + c], a);
  tmp[(size_t)b * CDIM + c] = a;
}

// ---------------- K5b: preds[b,cls] = tmp[b,:].labw[cls,:] + labb ----------------
__global__ __launch_bounds__(256) void k_pred2(
    const float* __restrict__ labw, const float* __restrict__ labb,
    const float* __restrict__ tmp, float* __restrict__ preds) {
  const int w = blockIdx.x * 4 + (threadIdx.x >> 6);
  const int lane = threadIdx.x & 63;
  const int b = w / NCLS, cls = w % NCLS;
  if (b >= BDIM) return;
  const float* tr = tmp + (size_t)b * CDIM;
  const float* wr = labw + (size_t)cls * CDIM;
  float a = 0.f;
#pragma unroll
  for (int c0 = 0; c0 < CDIM; c0 += 256) {
    float4 t = *(const float4*)&tr[c0 + lane * 4];
    float4 v = *(const float4*)&wr[c0 + lane * 4];
    a += t.x * v.x + t.y * v.y + t.z * v.z + t.w * v.w;
  }
#pragma unroll
  for (int off = 32; off > 0; off >>= 1) a += __shfl_down(a, off, 64);
  if (lane == 0) preds[b * NCLS + cls] = a + labb[cls];
}

extern "C" void kernel_launch(void* const* d_in, const int* in_sizes, int n_in,
                              void* d_out, int out_size, void* d_ws, size_t ws_size,
                              hipStream_t stream) {
  const float* x        = (const float*)d_in[0];
  const float* concepts = (const float*)d_in[1];
  const float* cfcw     = (const float*)d_in[2];
  const float* cfcb     = (const float*)d_in[3];
  const float* labw     = (const float*)d_in[4];
  const float* labb     = (const float*)d_in[5];

  float* out    = (float*)d_out;
  float* sm_out = out;                                  // [32][113][784]
  float* cs_out = out + (size_t)BDIM * KDIM * N2;       // [32][112]
  float* pr_out = cs_out + (size_t)BDIM * KC;           // [32][200]

  char* ws = (char*)d_ws;
  float*  csq  = (float*)(ws + 0);         // 128 f32          -> 512 B
  float*  part = (float*)(ws + 512);       // 32*7*112 f32     -> 100,352 B
  float*  tmp  = (float*)(ws + 100864);    // 32*2048 f32      -> 262,144 B
  ushort* cbf  = (ushort*)(ws + 363008);   // 128*2048 bf16    -> 524,288 B

  k_prep <<<dim3(128), dim3(256), 0, stream>>>(concepts, cbf, csq);
  k_fused<<<dim3(7, BDIM), dim3(512), 0, stream>>>(x, cbf, cfcw, csq, sm_out, part);
  k_sig  <<<dim3((BDIM * KC + 255) / 256), dim3(256), 0, stream>>>(part, cfcb, cs_out);
  k_tmp  <<<dim3(CDIM / 256, BDIM), dim3(256), 0, stream>>>(concepts, cs_out, tmp);
  k_pred2<<<dim3((BDIM * NCLS + 3) / 4), dim3(256), 0, stream>>>(labw, labb, tmp, pr_out);
}

// Round 9
// 100.199 us; speedup vs baseline: 1.4482x; 1.0329x over previous
//
#include <hip/hip_runtime.h>
#include <hip/hip_bf16.h>
#include <cstdint>

typedef __attribute__((ext_vector_type(8))) short short8;
typedef __attribute__((ext_vector_type(4))) float f32x4;

#define BDIM 32
#define CDIM 2048
#define NPIX 196    // 14*14
#define HIN 14
#define N2 784      // 28*28
#define W2 28
#define KDIM 113
#define KC 112
#define NCLS 200
#define BN 112      // cols per block; 7*112 = 784 exact
#define NSTEP 64    // 2048/32
#define SMLD 117    // Sm row stride (conflict-free)
#define PPAD 6276   // 32*196 + 4 pad (safe for the weight-0 pair over-read)

// ---------------- K_prep: concepts -> bf16, PRE-PERMUTED to LDS fragment order, + csq ----------------
__global__ __launch_bounds__(256) void k_prep(const float* __restrict__ concepts,
                                              ushort* __restrict__ cbf,
                                              float* __restrict__ csq) {
  int k = blockIdx.x, t = threadIdx.x;
  const int kt = k >> 4, lr = k & 15;
  float s = 0.f;
  for (int c = t; c < CDIM; c += 256) {
    float v = (k < KDIM) ? concepts[(size_t)k * CDIM + c] : 0.f;
    __hip_bfloat16 h = __float2bfloat16(v);
    int st = c >> 5, gs = (c >> 3) & 3, j = c & 7;
    cbf[((((size_t)st * 8 + kt) * 4 + gs) * 16 + lr) * 8 + j] = __bfloat16_as_ushort(h);
    float vb = __bfloat162float(h);
    s = fmaf(vb, vb, s);
  }
  __shared__ float r[4];
#pragma unroll
  for (int off = 32; off > 0; off >>= 1) s += __shfl_down(s, off, 64);
  if ((t & 63) == 0) r[t >> 6] = s;
  __syncthreads();
  if (t == 0) csq[k] = r[0] + r[1] + r[2] + r[3];
}

// ---------------- K_fused: XCD-local fused upsample + MFMA GEMM + softmax + logit partials ----------------
__global__ __launch_bounds__(512) void k_fused(
    const float* __restrict__ x,         // [32][2048][14][14]
    const ushort* __restrict__ cbf,      // pre-permuted bf16 concepts
    const float* __restrict__ cfcw,      // [2048]
    const float* __restrict__ csq,       // [128]
    float* __restrict__ attn_out,        // [32][113][784]
    float* __restrict__ part)            // [32][7][112]
{
  union alignas(16) SmemU {
    struct { float P[2][PPAD]; ushort A[2][4096]; ushort Bf[2][3584]; } s;  // 80.9 KB
    float Sm[128][SMLD];                                                    // 59.9 KB
  };
  __shared__ SmemU u;
  __shared__ float cfcw_s[CDIM];
  __shared__ float red[4][BN][2];
  __shared__ float xsq[BN], proj[BN], csq_s[KDIM], rinv_s[BN];

  const int tid = threadIdx.x;
  // XCD-aware decode: all 7 bx-blocks of image b land on the same XCD (wgid%8 round-robin)
  const int wgid = blockIdx.x;
  const int xcd = wgid & 7, slot = wgid >> 3;   // slot 0..27
  const int bq = slot / 7;                      // 0..3
  const int bx = slot - bq * 7;                 // 0..6
  const int b = xcd + 8 * bq;                   // 0..31
  const int n0 = bx * BN;
  const int lane = tid & 63, w = tid >> 6;   // wave w owns k-rows w*16..w*16+15
  const int lr = lane & 15, gs = lane >> 4;
  const bool bact = tid < 448;
  const int g = tid / BN;                    // channel group 0..3 (bact)
  const int nn = tid - g * BN;               // column 0..111
  const int boff = (((nn >> 4) * 4 + g) * 16 + (nn & 15)) * 8;

  // bilinear params for col n0+nn (src = 0.5*o - 0.25, edge-clamped), pair-read form
  int n = n0 + (bact ? nn : 0);
  int i2 = n / W2, j2 = n - i2 * W2;
  float si = 0.5f * i2 - 0.25f;
  float sj = 0.5f * j2 - 0.25f;
  float fif = floorf(si), fjf = floorf(sj);
  int ii = (int)fif, jj = (int)fjf;
  float fi = si - fif, fj = sj - fjf;
  int ia = ii < 0 ? 0 : ii;
  int ib = (ii + 1 > 13) ? 13 : (ii + 1);
  int ja = jj < 0 ? 0 : jj;
  int jb = (jj + 1 > 13) ? 13 : (jj + 1);
  float w00 = (1.f - fi) * (1.f - fj), w01 = (1.f - fi) * fj;
  float w10 = fi * (1.f - fj),         w11 = fi * fj;
  if (jb == ja) { w00 += w01; w01 = 0.f; w10 += w11; w11 = 0.f; }
  const int o00 = ia * HIN + ja;
  const int o10 = ib * HIN + ja;

  const float* xb = x + (size_t)b * CDIM * NPIX;
  float psq = 0.f, ppj = 0.f;

  f32x4 acc[7];
#pragma unroll
  for (int t = 0; t < 7; ++t) acc[t] = f32x4{0.f, 0.f, 0.f, 0.f};

  // blend step S: read P[S&1], write Bf[S&1], accumulate psq/ppj
#define BLEND(S_)                                                         \
  do {                                                                    \
    const int s_ = (S_);                                                  \
    const float* Pc = u.s.P[s_ & 1];                                      \
    const int cb0 = s_ * 32 + g * 8;                                      \
    uint us_[4];                                                          \
    _Pragma("unroll")                                                     \
    for (int p = 0; p < 4; ++p) {                                         \
      float vv[2];                                                        \
      _Pragma("unroll")                                                   \
      for (int h = 0; h < 2; ++h) {                                       \
        const int j = p * 2 + h;                                          \
        const float* pr = Pc + (g * 8 + j) * NPIX;                        \
        float a0 = pr[o00], a1 = pr[o00 + 1];                             \
        float b0 = pr[o10], b1 = pr[o10 + 1];                             \
        vv[h] = w00 * a0 + w01 * a1 + w10 * b0 + w11 * b1;                \
      }                                                                   \
      __hip_bfloat16 h0 = __float2bfloat16(vv[0]);                        \
      __hip_bfloat16 h1 = __float2bfloat16(vv[1]);                        \
      float v0 = __bfloat162float(h0), v1 = __bfloat162float(h1);         \
      psq = fmaf(v0, v0, psq);                                            \
      psq = fmaf(v1, v1, psq);                                            \
      ppj = fmaf(v0, cfcw_s[cb0 + p * 2], ppj);                           \
      ppj = fmaf(v1, cfcw_s[cb0 + p * 2 + 1], ppj);                       \
      us_[p] = (uint)__bfloat16_as_ushort(h0) |                           \
               ((uint)__bfloat16_as_ushort(h1) << 16);                    \
    }                                                                     \
    uint4 pk; pk.x = us_[0]; pk.y = us_[1]; pk.z = us_[2]; pk.w = us_[3]; \
    *(uint4*)&u.s.Bf[s_ & 1][boff] = pk;                                  \
  } while (0)

  // ---- prologue: stage P[0] (step 0), P[1] (step 1), A[0]; then blend step 0 ----
  {
    for (int i = tid; i < CDIM; i += 512) cfcw_s[i] = cfcw[i];
    if (tid < KDIM) csq_s[tid] = csq[tid];
    const float4* ps0 = (const float4*)xb;
    const float4* ps1 = (const float4*)(xb + 32 * NPIX);
    float4 r0 = ps0[tid], r1 = ps0[tid + 512], r2 = ps0[tid + 1024];
    float4 t0 = ps1[tid], t1 = ps1[tid + 512], t2 = ps1[tid + 1024];
    float4 r3 = {0,0,0,0}, t3 = {0,0,0,0};
    if (tid < 32) { r3 = ps0[tid + 1536]; t3 = ps1[tid + 1536]; }
    uint4 av0 = *(const uint4*)(cbf + (size_t)tid * 8);
    *(float4*)&u.s.P[0][tid * 4] = r0;
    *(float4*)&u.s.P[0][(tid + 512) * 4] = r1;
    *(float4*)&u.s.P[0][(tid + 1024) * 4] = r2;
    *(float4*)&u.s.P[1][tid * 4] = t0;
    *(float4*)&u.s.P[1][(tid + 512) * 4] = t1;
    *(float4*)&u.s.P[1][(tid + 1024) * 4] = t2;
    if (tid < 32) {
      *(float4*)&u.s.P[0][(tid + 1536) * 4] = r3;
      *(float4*)&u.s.P[1][(tid + 1536) * 4] = t3;
    }
    *(uint4*)&u.s.A[0][tid * 8] = av0;
    __syncthreads();
    if (bact) BLEND(0);
    __syncthreads();
  }

  // ---- main loop: ONE barrier per step ----
  // iter s: issue x(s+2), cbf(s+1) | blend(s+1) | MFMA(s) | write P(s+2), A(s+1) | barrier
  for (int s = 0; s < NSTEP; ++s) {
    const bool m1 = (s + 1) < NSTEP;
    const bool m2 = (s + 2) < NSTEP;
    float4 q0, q1, q2, q3 = {0,0,0,0};
    uint4 av;
    if (m2) {
      const float4* ps = (const float4*)(xb + (size_t)(s + 2) * 32 * NPIX);
      q0 = ps[tid]; q1 = ps[tid + 512]; q2 = ps[tid + 1024];
      if (tid < 32) q3 = ps[tid + 1536];
    }
    if (m1) av = *(const uint4*)(cbf + (size_t)(s + 1) * 4096 + tid * 8);
    if (m1 && bact) BLEND(s + 1);
    {
      const int cur = s & 1;
      short8 af = *(const short8*)&u.s.A[cur][w * 512 + lane * 8];
#pragma unroll
      for (int t = 0; t < 7; ++t) {
        short8 bfr = *(const short8*)&u.s.Bf[cur][t * 512 + lane * 8];
        acc[t] = __builtin_amdgcn_mfma_f32_16x16x32_bf16(af, bfr, acc[t], 0, 0, 0);
      }
    }
    if (m2) {
      const int pn = s & 1;  // (s+2)&1
      *(float4*)&u.s.P[pn][tid * 4] = q0;
      *(float4*)&u.s.P[pn][(tid + 512) * 4] = q1;
      *(float4*)&u.s.P[pn][(tid + 1024) * 4] = q2;
      if (tid < 32) *(float4*)&u.s.P[pn][(tid + 1536) * 4] = q3;
    }
    if (m1) {
      *(uint4*)&u.s.A[(s + 1) & 1][tid * 8] = av;
      __syncthreads();
    }
  }
#undef BLEND

  // ---- reduce x_sq / proj across the 4 channel-groups ----
  if (bact) { red[g][nn][0] = psq; red[g][nn][1] = ppj; }
  __syncthreads();
  if (tid < BN) {
    float sq = 0.f, pj = 0.f;
#pragma unroll
    for (int gg = 0; gg < 4; ++gg) { sq += red[gg][tid][0]; pj += red[gg][tid][1]; }
    xsq[tid] = sq; proj[tid] = pj;
  }
  __syncthreads();

  // ---- d2 -> -dist into Sm (C/D layout: col=lane&15, row=(lane>>4)*4+reg) ----
#pragma unroll
  for (int t = 0; t < 7; ++t) {
    int col = t * 16 + lr;
#pragma unroll
    for (int q = 0; q < 4; ++q) {
      int k = w * 16 + gs * 4 + q;
      if (k < KDIM) {
        float d2 = csq_s[k] + xsq[col] - 2.f * acc[t][q];
        u.Sm[k][col] = -sqrtf(fmaxf(d2, 0.f));
      }
    }
  }
  __syncthreads();

  // ---- softmax: 4 lanes per column (quad shfl_xor reductions) ----
  {
    const int col = tid >> 2, sub = tid & 3;
    if (col < BN) {
      float m = -1e30f;
      for (int k = sub; k < KDIM; k += 4) m = fmaxf(m, u.Sm[k][col]);
      m = fmaxf(m, __shfl_xor(m, 1, 64));
      m = fmaxf(m, __shfl_xor(m, 2, 64));
      float ssum = 0.f;
      for (int k = sub; k < KDIM; k += 4) {
        float e = __expf(u.Sm[k][col] - m);
        u.Sm[k][col] = e;
        ssum += e;
      }
      ssum += __shfl_xor(ssum, 1, 64);
      ssum += __shfl_xor(ssum, 2, 64);
      if (sub == 0) rinv_s[col] = 1.f / ssum;
    }
  }
  __syncthreads();

  // ---- normalize + write attn: coalesced lane sweep over columns ----
  {
    const int col2 = tid & 127, kr = tid >> 7;
    if (col2 < BN) {
      const float rv = rinv_s[col2];
      float* op = attn_out + (size_t)b * KDIM * N2 + n0 + col2;
      for (int k = kr; k < KDIM; k += 4) {
        float a2 = u.Sm[k][col2] * rv;
        u.Sm[k][col2] = a2;
        op[(size_t)k * N2] = a2;
      }
    }
  }
  __syncthreads();

  // ---- logit partials: quad-parallel over columns ----
  if (tid < KC * 4) {
    const int k = tid >> 2, sub = tid & 3;
    float lg = 0.f;
    for (int c2 = sub; c2 < BN; c2 += 4) lg = fmaf(u.Sm[k][c2], proj[c2], lg);
    lg += __shfl_xor(lg, 1, 64);
    lg += __shfl_xor(lg, 2, 64);
    if (sub == 0) part[((size_t)b * 7 + bx) * KC + k] = lg;
  }
}

// ---------------- K4: reduce partials -> sigmoid -> concept_scores ----------------
__global__ void k_sig(const float* __restrict__ part, const float* __restrict__ cfcb,
                      float* __restrict__ cs_out) {
  int i = blockIdx.x * blockDim.x + threadIdx.x;
  if (i >= BDIM * KC) return;
  int b = i / KC, k = i % KC;
  float l = cfcb[0];
#pragma unroll
  for (int t = 0; t < 7; ++t) l += part[((size_t)b * 7 + t) * KC + k];
  cs_out[i] = 1.f / (1.f + __expf(-l));
}

// ---------------- K5a: tmp[b,c] = sum_k cs[b,k] * concepts[k,c] ----------------
__global__ __launch_bounds__(256) void k_tmp(
    const float* __restrict__ concepts, const float* __restrict__ cs,
    float* __restrict__ tmp) {
  __shared__ float cs_s[KC];
  const int b = blockIdx.y;
  const int c = blockIdx.x * 256 + threadIdx.x;
  if (threadIdx.x < KC) cs_s[threadIdx.x] = cs[b * KC + threadIdx.x];
  __syncthreads();
  float a = 0.f;
#pragma unroll 8
  for (int k = 0; k < KC; ++k) a = fmaf(cs_s[k], concepts[(size_t)k * CDIM + c], a);
  tmp[(size_t)b * CDIM + c] = a;
}

// ---------------- K5b: preds[b,cls] = tmp[b,:].labw[cls,:] + labb ----------------
__global__ __launch_bounds__(256) void k_pred2(
    const float* __restrict__ labw, const float* __restrict__ labb,
    const float* __restrict__ tmp, float* __restrict__ preds) {
  const int w = blockIdx.x * 4 + (threadIdx.x >> 6);
  const int lane = threadIdx.x & 63;
  const int b = w / NCLS, cls = w % NCLS;
  if (b >= BDIM) return;
  const float* tr = tmp + (size_t)b * CDIM;
  const float* wr = labw + (size_t)cls * CDIM;
  float a = 0.f;
#pragma unroll
  for (int c0 = 0; c0 < CDIM; c0 += 256) {
    float4 t = *(const float4*)&tr[c0 + lane * 4];
    float4 v = *(const float4*)&wr[c0 + lane * 4];
    a += t.x * v.x + t.y * v.y + t.z * v.z + t.w * v.w;
  }
#pragma unroll
  for (int off = 32; off > 0; off >>= 1) a += __shfl_down(a, off, 64);
  if (lane == 0) preds[b * NCLS + cls] = a + labb[cls];
}

extern "C" void kernel_launch(void* const* d_in, const int* in_sizes, int n_in,
                              void* d_out, int out_size, void* d_ws, size_t ws_size,
                              hipStream_t stream) {
  const float* x        = (const float*)d_in[0];
  const float* concepts = (const float*)d_in[1];
  const float* cfcw     = (const float*)d_in[2];
  const float* cfcb     = (const float*)d_in[3];
  const float* labw     = (const float*)d_in[4];
  const float* labb     = (const float*)d_in[5];

  float* out    = (float*)d_out;
  float* sm_out = out;                                  // [32][113][784]
  float* cs_out = out + (size_t)BDIM * KDIM * N2;       // [32][112]
  float* pr_out = cs_out + (size_t)BDIM * KC;           // [32][200]

  char* ws = (char*)d_ws;
  float*  csq  = (float*)(ws + 0);         // 128 f32          -> 512 B
  float*  part = (float*)(ws + 512);       // 32*7*112 f32     -> 100,352 B
  float*  tmp  = (float*)(ws + 100864);    // 32*2048 f32      -> 262,144 B
  ushort* cbf  = (ushort*)(ws + 363008);   // 128*2048 bf16    -> 524,288 B

  k_prep <<<dim3(128), dim3(256), 0, stream>>>(concepts, cbf, csq);
  k_fused<<<dim3(224), dim3(512), 0, stream>>>(x, cbf, cfcw, csq, sm_out, part);
  k_sig  <<<dim3((BDIM * KC + 255) / 256), dim3(256), 0, stream>>>(part, cfcb, cs_out);
  k_tmp  <<<dim3(CDIM / 256, BDIM), dim3(256), 0, stream>>>(concepts, cs_out, tmp);
  k_pred2<<<dim3((BDIM * NCLS + 3) / 4), dim3(256), 0, stream>>>(labw, labb, tmp, pr_out);
}